// Round 8
// baseline (1697.113 us; speedup 1.0000x reference)
//
#include <hip/hip_runtime.h>
#include <stdint.h>

// ---------------- problem constants ----------------
constexpr int TT = 128;    // time steps
constexpr int BB = 256;    // batch
constexpr int LL = 1024;   // hidden dim
constexpr int NG = 4096;   // 4 gates * LL
constexpr int VV = 95;     // vocab

typedef short bf16x8  __attribute__((ext_vector_type(8)));
typedef float f32x4   __attribute__((ext_vector_type(4)));
typedef float f32x16  __attribute__((ext_vector_type(16)));

typedef __attribute__((address_space(1))) const uint32_t gu32;
typedef __attribute__((address_space(3))) uint32_t lu32;

__device__ __forceinline__ unsigned short f2bf(float f) {
    unsigned int u = __builtin_bit_cast(unsigned int, f);
    unsigned int r = (u + 0x7FFFu + ((u >> 16) & 1u)) >> 16;
    return (unsigned short)r;
}
__device__ __forceinline__ float bf2f(unsigned short h) {
    unsigned int u = ((unsigned int)h) << 16;
    return __builtin_bit_cast(float, u);
}
__device__ __forceinline__ float sigmoidf_(float x) {
    return 1.0f / (1.0f + __expf(-x));
}
__device__ __forceinline__ float tanhf_(float x) {
    return 1.0f - 2.0f / (__expf(2.0f * x) + 1.0f);
}

// ---------------- prep: W split ----------------
// Recurrent half -> Wimg, per-lt LDS image (131072 B), lane-linear for 32x32x16:
//   nl = gate*16 + (l&15) (0..63), k in 0..1023
//   byte = lt*131072 + (k>>4)*2048 + (nl>>5)*1024 + (((k>>3)&1)*32 + (nl&31))*16 + (k&7)*2
// (wave (.,wn) lane reads chunk_base + wn*1024 + lane*16 -> B[k][n] frag, conflict-free)
// Embedding half -> Wemb hi/lo, row-major [row][k], row = lt*64 + nl.
__global__ void prep_w_all(const float* __restrict__ Wf, const float* __restrict__ Wi,
                           const float* __restrict__ Wo, const float* __restrict__ Wc,
                           unsigned short* __restrict__ Wimg,
                           unsigned short* __restrict__ Wemb_hi,
                           unsigned short* __restrict__ Wemb_lo) {
    int idx = blockIdx.x * 256 + threadIdx.x;
    const int total = NG * 2048;  // 8M
    for (; idx < total; idx += gridDim.x * 256) {
        int row = idx >> 11;        // 0..4095
        int col = idx & 2047;       // 0..2047
        int lt   = row >> 6;
        int nl   = row & 63;
        int gate = nl >> 4;
        int l    = lt * 16 + (nl & 15);
        const float* W = (gate == 0) ? Wf : (gate == 1) ? Wi : (gate == 2) ? Wo : Wc;
        float w = W[l * 2048 + col];
        if (col >= 1024) {
            int k = col - 1024;
            size_t byte = (size_t)lt * 131072 + (size_t)(k >> 4) * 2048 + (nl >> 5) * 1024
                        + ((((k >> 3) & 1) << 5) + (nl & 31)) * 16 + (k & 7) * 2;
            *(unsigned short*)((char*)Wimg + byte) = f2bf(w);
        } else {
            unsigned short hi = f2bf(w);
            float lo = w - bf2f(hi);
            Wemb_hi[row * 1024 + col] = hi;
            Wemb_lo[row * 1024 + col] = f2bf(lo);
        }
    }
}

// ---------------- prep: emb hi/lo split, padded to 96 rows ----------------
__global__ void prep_emb_split(const float* __restrict__ emb,
                               unsigned short* __restrict__ Eh,
                               unsigned short* __restrict__ El) {
    int idx = blockIdx.x * 256 + threadIdx.x;   // 96*1024 threads
    int v = idx >> 10;
    float w = (v < VV) ? emb[idx] : 0.0f;
    unsigned short hi = f2bf(w);
    Eh[idx] = hi;
    El[idx] = f2bf(w - bf2f(hi));
}

// ---------------- prep: gate_pre2[v][l][gate] via hi/lo MFMA (16x16x32) ------
__global__ __launch_bounds__(128)
void gate_pre_mfma(const unsigned short* __restrict__ Eh, const unsigned short* __restrict__ El,
                   const unsigned short* __restrict__ Wh, const unsigned short* __restrict__ Wl,
                   const float* __restrict__ bfv, const float* __restrict__ biv,
                   const float* __restrict__ bov, const float* __restrict__ bcv,
                   float* __restrict__ gp2) {
    const int lt   = blockIdx.x;
    const int tid  = threadIdx.x;
    const int lane = tid & 63;
    const int wm   = tid >> 6;
    const int l15  = lane & 15;
    const int kq   = lane >> 4;          // 0..3

    f32x4 acc[3][4];
    #pragma unroll
    for (int mf = 0; mf < 3; ++mf)
        #pragma unroll
        for (int nf = 0; nf < 4; ++nf) acc[mf][nf] = (f32x4){0.f, 0.f, 0.f, 0.f};

    #pragma unroll 2
    for (int ks = 0; ks < 32; ++ks) {
        const int k0 = ks * 32 + kq * 8;
        bf16x8 ah[3], al[3], bh[4], bl[4];
        #pragma unroll
        for (int mf = 0; mf < 3; ++mf) {
            const size_t ao = (size_t)(wm * 48 + mf * 16 + l15) * 1024 + k0;
            ah[mf] = *(const bf16x8*)(Eh + ao);
            al[mf] = *(const bf16x8*)(El + ao);
        }
        #pragma unroll
        for (int nf = 0; nf < 4; ++nf) {
            const size_t bo = (size_t)(lt * 64 + nf * 16 + l15) * 1024 + k0;
            bh[nf] = *(const bf16x8*)(Wh + bo);
            bl[nf] = *(const bf16x8*)(Wl + bo);
        }
        #pragma unroll
        for (int mf = 0; mf < 3; ++mf)
            #pragma unroll
            for (int nf = 0; nf < 4; ++nf) {
                acc[mf][nf] = __builtin_amdgcn_mfma_f32_16x16x32_bf16(ah[mf], bh[nf], acc[mf][nf], 0, 0, 0);
                acc[mf][nf] = __builtin_amdgcn_mfma_f32_16x16x32_bf16(ah[mf], bl[nf], acc[mf][nf], 0, 0, 0);
                acc[mf][nf] = __builtin_amdgcn_mfma_f32_16x16x32_bf16(al[mf], bh[nf], acc[mf][nf], 0, 0, 0);
            }
    }

    const int lgl = lt * 16 + l15;
    #pragma unroll
    for (int nf = 0; nf < 4; ++nf) {
        const float* bias = (nf == 0) ? bfv : (nf == 1) ? biv : (nf == 2) ? bov : bcv;
        const float bv = bias[lgl];
        #pragma unroll
        for (int mf = 0; mf < 3; ++mf)
            #pragma unroll
            for (int r = 0; r < 4; ++r) {
                const int v = wm * 48 + mf * 16 + kq * 4 + r;
                if (v < VV)
                    gp2[((size_t)v * LL + lgl) * 4 + nf] = acc[mf][nf][r] + bv;
            }
    }
}

// ---------------- prep: init h0 (bf16) and c (=0; layout [l][b]) -------------
__global__ void init_state(const float* __restrict__ h_init,
                           unsigned short* __restrict__ h0, float* __restrict__ c) {
    int idx = blockIdx.x * 256 + threadIdx.x;   // 1024*256 = BB*LL
    h0[idx] = f2bf(h_init[idx]);
    c[idx] = 0.f;
}

// ---------------- per-timestep kernel (32x32x16 MFMA) ----------------
// grid 256 (bt=blk>>6, lt=blk&63), 256 threads = 4 waves; wave wv=(wm,wn) owns
// quadrant m-rows wm*32..+31, n-cols wn*32..+31. 64 ks-steps of K=16; per ks:
// 1 A global b128 + 1 ds_read_b128 + 1 MFMA. 8 phases, counted vmcnt(12),
// raw s_barrier. Epilogue via 16.9 KB g_s reshuffle (4 gates x 4 rows/thread).
__global__ __launch_bounds__(256, 1)
void lstm_step6(const unsigned short* __restrict__ Wimg,
                const float* __restrict__ gp2,
                const int* __restrict__ x_t,
                const unsigned short* __restrict__ h_in,
                unsigned short* __restrict__ h_out,
                float* __restrict__ c_ws,        // layout [l*BB + b]
                float* __restrict__ out_t) {
    __shared__ unsigned short wlds_s[65536];   // 128 KiB W image
    __shared__ float g_s[64 * 66 + 8];         // 16.9 KiB gate reshuffle
    char* wlds = (char*)wlds_s;

    const int tid  = threadIdx.x;
    const int lane = tid & 63;
    const int wv   = tid >> 6;
    const int wm   = wv >> 1;                  // m-half
    const int wn   = wv & 1;                   // n-half
    const int bt   = blockIdx.x >> 6;
    const int lt   = blockIdx.x & 63;
    const int c31  = lane & 31;
    const int kh   = lane >> 5;

    // epilogue thread mapping: thread owns l = lt*16+(tid&15), rows b0..b0+3
    const int l15r = tid & 15;
    const int m0   = (tid >> 4) * 4;           // 0..60
    const int le   = lt * 16 + l15r;
    const int b0   = bt * 64 + m0;

    const char* aptr = (const char*)h_in + (size_t)(bt * 64 + wm * 32 + c31) * 2048 + kh * 16;
    const char* wsrc = (const char*)Wimg + (size_t)lt * 131072 + tid * 16;
    const char* bbase = wlds + wn * 1024 + lane * 16;

    bf16x8 aA[8], aB[8];
    f32x16 acc;
    #pragma unroll
    for (int e = 0; e < 16; ++e) acc[e] = 0.f;

    #define SB __builtin_amdgcn_sched_barrier(0);

    #define LOAD_A(dst, g)                                                   \
        _Pragma("unroll") for (int ki = 0; ki < 8; ++ki)                     \
            dst[ki] = *(const bf16x8*)(aptr + ((g) * 8 + ki) * 32);

    #define STAGE(g)                                                         \
        _Pragma("unroll") for (int j = (g) * 4; j < (g) * 4 + 4; ++j)        \
            __builtin_amdgcn_global_load_lds((gu32*)(wsrc + j * 4096),       \
                                             (lu32*)(wlds + j * 4096 + wv * 1024), \
                                             16, 0, 0);

    #define QCOMP(areg, g)                                                   \
        _Pragma("unroll") for (int ki = 0; ki < 8; ++ki) {                   \
            const int ks = (g) * 8 + ki;                                     \
            bf16x8 bw = *(const bf16x8*)(bbase + ks * 2048);                 \
            acc = __builtin_amdgcn_mfma_f32_32x32x16_bf16(areg[ki], bw, acc, 0, 0, 0); \
        }

    #define WAITQ(N)                                                         \
        asm volatile("s_waitcnt vmcnt(" #N ")" ::: "memory");                \
        __builtin_amdgcn_s_barrier();                                        \
        __builtin_amdgcn_sched_barrier(0);

    // ---- prologue: epilogue x,c prefetch (2 oldest vmem ops) ----
    const int4 xt4 = *(const int4*)(x_t + b0);
    const float4 cv = *(const float4*)(c_ws + (size_t)le * BB + b0);
    SB
    LOAD_A(aA, 0) SB
    STAGE(0)      SB
    LOAD_A(aB, 1) SB
    STAGE(1)      SB
    // issued: 26

    WAITQ(12)  STAGE(2) SB QCOMP(aA, 0) SB LOAD_A(aA, 2) SB   // issued 38
    WAITQ(12)  STAGE(3) SB QCOMP(aB, 1) SB LOAD_A(aB, 3) SB   // issued 50
    WAITQ(12)  STAGE(4) SB QCOMP(aA, 2) SB LOAD_A(aA, 4) SB   // issued 62
    WAITQ(12)  STAGE(5) SB QCOMP(aB, 3) SB LOAD_A(aB, 5) SB   // issued 74
    WAITQ(12)  STAGE(6) SB QCOMP(aA, 4) SB LOAD_A(aA, 6) SB   // issued 86
    WAITQ(12)  STAGE(7) SB QCOMP(aB, 5) SB LOAD_A(aB, 7) SB   // issued 98

    WAITQ(12)
    // gp gather overlaps Q6 (x long resident)
    float4 gpv[4];
    {
        const int vr[4] = {xt4.x, xt4.y, xt4.z, xt4.w};
        #pragma unroll
        for (int r = 0; r < 4; ++r)
            gpv[r] = *(const float4*)(gp2 + ((size_t)vr[r] * LL + le) * 4);
    }
    SB
    QCOMP(aA, 6) SB                                           // issued 102

    WAITQ(4)
    QCOMP(aB, 7)

    #undef LOAD_A
    #undef STAGE
    #undef QCOMP
    #undef WAITQ
    #undef SB

    // ---- reshuffle: C/D 32x32 layout col=lane&31, row=(e&3)+8*(e>>2)+4*kh ----
    {
        const int fcol = (wn * 32 + c31) * 66 + wm * 32 + kh * 4;
        #pragma unroll
        for (int q = 0; q < 4; ++q) {
            *(float4*)&g_s[fcol + q * 8] =
                (float4){acc[4 * q + 0], acc[4 * q + 1], acc[4 * q + 2], acc[4 * q + 3]};
        }
    }
    __syncthreads();

    // ---- cell update: thread owns l=le, rows b0..b0+3 ----
    float gvv[4][4];
    #pragma unroll
    for (int gate = 0; gate < 4; ++gate) {
        const float4 q0 = *(const float4*)&g_s[(gate * 16 + l15r) * 66 + m0];
        gvv[gate][0] = q0.x; gvv[gate][1] = q0.y; gvv[gate][2] = q0.z; gvv[gate][3] = q0.w;
    }

    const float cold[4] = {cv.x, cv.y, cv.z, cv.w};
    float cnew[4], hnew[4];
    #pragma unroll
    for (int r = 0; r < 4; ++r) {
        const float gf = gvv[0][r] + gpv[r].x;
        const float gi = gvv[1][r] + gpv[r].y;
        const float go = gvv[2][r] + gpv[r].z;
        const float gc = gvv[3][r] + gpv[r].w;
        const float cn = sigmoidf_(gf) * cold[r] + sigmoidf_(gi) * tanhf_(gc);
        hnew[r] = sigmoidf_(go) * tanhf_(cn);
        cnew[r] = cn;
    }
    *(float4*)(c_ws + (size_t)le * BB + b0) = (float4){cnew[0], cnew[1], cnew[2], cnew[3]};
    #pragma unroll
    for (int r = 0; r < 4; ++r) {
        const size_t off = (size_t)(b0 + r) * LL + le;
        out_t[off] = hnew[r];
        h_out[off] = f2bf(hnew[r]);
    }
}

// ---------------- launch ----------------
extern "C" void kernel_launch(void* const* d_in, const int* in_sizes, int n_in,
                              void* d_out, int out_size, void* d_ws, size_t ws_size,
                              hipStream_t stream) {
    const int*   x      = (const int*)d_in[0];
    const float* h_init = (const float*)d_in[1];
    const float* emb    = (const float*)d_in[2];
    const float* Wf     = (const float*)d_in[3];
    const float* bfv    = (const float*)d_in[4];
    const float* Wi     = (const float*)d_in[5];
    const float* biv    = (const float*)d_in[6];
    const float* Wo     = (const float*)d_in[7];
    const float* bov    = (const float*)d_in[8];
    const float* Wc     = (const float*)d_in[9];
    const float* bcv    = (const float*)d_in[10];
    float* out = (float*)d_out;

    char* ws = (char*)d_ws;
    unsigned short* Wimg    = (unsigned short*)(ws);                 // 8 MB
    unsigned short* Wemb_hi = (unsigned short*)(ws + 8388608);       // 8 MB
    unsigned short* Wemb_lo = (unsigned short*)(ws + 16777216);      // 8 MB
    unsigned short* Eh      = (unsigned short*)(ws + 25165824);      // 192 KB
    unsigned short* El      = (unsigned short*)(ws + 25362432);      // 192 KB
    float*          gp2     = (float*)(ws + 25559040);               // 1.5 MB
    float*          c_ws    = (float*)(ws + 27131904);               // 1 MB
    unsigned short* hb0     = (unsigned short*)(ws + 28180480);      // 512 KB
    unsigned short* hb1     = (unsigned short*)(ws + 28704768);      // 512 KB

    prep_w_all<<<4096, 256, 0, stream>>>(Wf, Wi, Wo, Wc, Wimg, Wemb_hi, Wemb_lo);
    prep_emb_split<<<384, 256, 0, stream>>>(emb, Eh, El);
    gate_pre_mfma<<<64, 128, 0, stream>>>(Eh, El, Wemb_hi, Wemb_lo,
                                          bfv, biv, bov, bcv, gp2);
    init_state<<<1024, 256, 0, stream>>>(h_init, hb0, c_ws);

    unsigned short* hin = hb0;
    unsigned short* hout = hb1;
    for (int t = 0; t < TT; ++t) {
        lstm_step6<<<256, 256, 0, stream>>>(Wimg, gp2, x + t * BB,
                                            hin, hout, c_ws,
                                            out + (size_t)t * BB * LL);
        unsigned short* tmp = hin; hin = hout; hout = tmp;
    }
}

// Round 9
// 1037.911 us; speedup vs baseline: 1.6351x; 1.6351x over previous
//
#include <hip/hip_runtime.h>
#include <stdint.h>

// ---------------- problem constants ----------------
constexpr int TT = 128;    // time steps
constexpr int BB = 256;    // batch
constexpr int LL = 1024;   // hidden dim
constexpr int NG = 4096;   // 4 gates * LL
constexpr int VV = 95;     // vocab

typedef short bf16x8 __attribute__((ext_vector_type(8)));
typedef float f32x4  __attribute__((ext_vector_type(4)));

typedef __attribute__((address_space(1))) const uint32_t gu32;
typedef __attribute__((address_space(3))) uint32_t lu32;

__device__ __forceinline__ unsigned short f2bf(float f) {
    unsigned int u = __builtin_bit_cast(unsigned int, f);
    unsigned int r = (u + 0x7FFFu + ((u >> 16) & 1u)) >> 16;
    return (unsigned short)r;
}
__device__ __forceinline__ float bf2f(unsigned short h) {
    unsigned int u = ((unsigned int)h) << 16;
    return __builtin_bit_cast(float, u);
}
__device__ __forceinline__ float sigmoidf_(float x) {
    return 1.0f / (1.0f + __expf(-x));
}
__device__ __forceinline__ float tanhf_(float x) {
    return 1.0f - 2.0f / (__expf(2.0f * x) + 1.0f);
}

// ---------------- prep: W split (R4 image layout) ----------------
// Recurrent half -> Wimg, per-lt LDS image (131072 B):
//   byte = lt*131072 + (k>>5)*4096 + nl*64 + (k&31)*2,  nl = gate*16 + (l&15)
// Embedding half -> Wemb hi/lo, row-major [row][k], row = lt*64 + nl.
__global__ void prep_w_all(const float* __restrict__ Wf, const float* __restrict__ Wi,
                           const float* __restrict__ Wo, const float* __restrict__ Wc,
                           unsigned short* __restrict__ Wimg,
                           unsigned short* __restrict__ Wemb_hi,
                           unsigned short* __restrict__ Wemb_lo) {
    int idx = blockIdx.x * 256 + threadIdx.x;
    const int total = NG * 2048;  // 8M
    for (; idx < total; idx += gridDim.x * 256) {
        int row = idx >> 11;        // 0..4095
        int col = idx & 2047;       // 0..2047
        int lt   = row >> 6;
        int nl   = row & 63;
        int gate = nl >> 4;
        int l    = lt * 16 + (nl & 15);
        const float* W = (gate == 0) ? Wf : (gate == 1) ? Wi : (gate == 2) ? Wo : Wc;
        float w = W[l * 2048 + col];
        if (col >= 1024) {
            int k = col - 1024;
            size_t byte = (size_t)lt * 131072 + (size_t)(k >> 5) * 4096 + nl * 64 + (k & 31) * 2;
            *(unsigned short*)((char*)Wimg + byte) = f2bf(w);
        } else {
            unsigned short hi = f2bf(w);
            float lo = w - bf2f(hi);
            Wemb_hi[row * 1024 + col] = hi;
            Wemb_lo[row * 1024 + col] = f2bf(lo);
        }
    }
}

// ---------------- prep: emb hi/lo split, padded to 96 rows ----------------
__global__ void prep_emb_split(const float* __restrict__ emb,
                               unsigned short* __restrict__ Eh,
                               unsigned short* __restrict__ El) {
    int idx = blockIdx.x * 256 + threadIdx.x;   // 96*1024 threads
    int v = idx >> 10;
    float w = (v < VV) ? emb[idx] : 0.0f;
    unsigned short hi = f2bf(w);
    Eh[idx] = hi;
    El[idx] = f2bf(w - bf2f(hi));
}

// ---------------- prep: gate_pre2[v][l][gate] via hi/lo MFMA ----------------
__global__ __launch_bounds__(128)
void gate_pre_mfma(const unsigned short* __restrict__ Eh, const unsigned short* __restrict__ El,
                   const unsigned short* __restrict__ Wh, const unsigned short* __restrict__ Wl,
                   const float* __restrict__ bfv, const float* __restrict__ biv,
                   const float* __restrict__ bov, const float* __restrict__ bcv,
                   float* __restrict__ gp2) {
    const int lt   = blockIdx.x;
    const int tid  = threadIdx.x;
    const int lane = tid & 63;
    const int wm   = tid >> 6;
    const int l15  = lane & 15;
    const int kq   = lane >> 4;          // 0..3

    f32x4 acc[3][4];
    #pragma unroll
    for (int mf = 0; mf < 3; ++mf)
        #pragma unroll
        for (int nf = 0; nf < 4; ++nf) acc[mf][nf] = (f32x4){0.f, 0.f, 0.f, 0.f};

    #pragma unroll 2
    for (int ks = 0; ks < 32; ++ks) {
        const int k0 = ks * 32 + kq * 8;
        bf16x8 ah[3], al[3], bh[4], bl[4];
        #pragma unroll
        for (int mf = 0; mf < 3; ++mf) {
            const size_t ao = (size_t)(wm * 48 + mf * 16 + l15) * 1024 + k0;
            ah[mf] = *(const bf16x8*)(Eh + ao);
            al[mf] = *(const bf16x8*)(El + ao);
        }
        #pragma unroll
        for (int nf = 0; nf < 4; ++nf) {
            const size_t bo = (size_t)(lt * 64 + nf * 16 + l15) * 1024 + k0;
            bh[nf] = *(const bf16x8*)(Wh + bo);
            bl[nf] = *(const bf16x8*)(Wl + bo);
        }
        #pragma unroll
        for (int mf = 0; mf < 3; ++mf)
            #pragma unroll
            for (int nf = 0; nf < 4; ++nf) {
                acc[mf][nf] = __builtin_amdgcn_mfma_f32_16x16x32_bf16(ah[mf], bh[nf], acc[mf][nf], 0, 0, 0);
                acc[mf][nf] = __builtin_amdgcn_mfma_f32_16x16x32_bf16(ah[mf], bl[nf], acc[mf][nf], 0, 0, 0);
                acc[mf][nf] = __builtin_amdgcn_mfma_f32_16x16x32_bf16(al[mf], bh[nf], acc[mf][nf], 0, 0, 0);
            }
    }

    const int lgl = lt * 16 + l15;
    #pragma unroll
    for (int nf = 0; nf < 4; ++nf) {
        const float* bias = (nf == 0) ? bfv : (nf == 1) ? biv : (nf == 2) ? bov : bcv;
        const float bv = bias[lgl];
        #pragma unroll
        for (int mf = 0; mf < 3; ++mf)
            #pragma unroll
            for (int r = 0; r < 4; ++r) {
                const int v = wm * 48 + mf * 16 + kq * 4 + r;
                if (v < VV)
                    gp2[((size_t)v * LL + lgl) * 4 + nf] = acc[mf][nf][r] + bv;
            }
    }
}

// ---------------- prep: init h0 (bf16) and zero sync flags ----------------
__global__ void init_state(const float* __restrict__ h_init,
                           unsigned short* __restrict__ h0,
                           unsigned int* __restrict__ flags) {
    int idx = blockIdx.x * 256 + threadIdx.x;   // 1024*256 = BB*LL
    h0[idx] = f2bf(h_init[idx]);
    if (idx < 4096) flags[idx] = 0;             // 256 block-flags, 64B-strided
}

// ---------------- persistent LSTM, flag-synced ----------------
// grid 256 (bt=blk>>6, lt=blk&63) cooperative, 256 thr = 4 waves.
// 4 independent 64-block chains (one per bt). W LDS-resident for all steps;
// c in registers. Per step: per-quarter flag-poll (16 producers each) ->
// sc0sc1 A loads -> ds_read+MFMA -> epilogue -> sc0sc1 h stores -> vmcnt(0)
// -> syncthreads -> atomicExch(flag, t+1). No kernel boundaries, no grid.sync.
__global__ __launch_bounds__(256, 1)
void lstm_all(const unsigned short* __restrict__ Wimg,
              const float* __restrict__ gp2,
              const int* __restrict__ x,
              unsigned short* __restrict__ hb0,
              unsigned short* __restrict__ hb1,
              float* __restrict__ out,
              unsigned int* __restrict__ flags) {
    __shared__ unsigned short wlds_s[65536];   // 128 KiB
    char* wlds = (char*)wlds_s;

    const int tid  = threadIdx.x;
    const int lane = tid & 63;
    const int wv   = tid >> 6;
    const int bt   = blockIdx.x >> 6;
    const int lt   = blockIdx.x & 63;
    const int l15  = lane & 15;
    const int kq   = lane >> 4;

    const int l  = lt * 16 + l15;
    const int b0 = bt * 64 + wv * 16 + kq * 4;

    // ---- stage W into LDS once ----
    {
        const char* wsrc = (const char*)Wimg + (size_t)lt * 131072 + tid * 16;
        #pragma unroll
        for (int j = 0; j < 32; ++j)
            __builtin_amdgcn_global_load_lds((gu32*)(wsrc + j * 4096),
                                             (lu32*)(wlds + j * 4096 + wv * 1024),
                                             16, 0, 0);
        asm volatile("s_waitcnt vmcnt(0)" ::: "memory");
        __syncthreads();
    }
    const char* bbase = wlds + l15 * 64 + kq * 16;

    // per-step-invariant addresses
    const size_t arow = (size_t)(bt * 64 + wv * 16 + l15) * 2048 + kq * 16;
    const char* aptr0 = (const char*)hb0 + arow;
    const char* aptr1 = (const char*)hb1 + arow;
    const unsigned int* fp[4];
    #pragma unroll
    for (int q = 0; q < 4; ++q) fp[q] = flags + (((bt << 6) + (q << 4) + l15) << 4);
    const int myflag = ((bt << 6) + lt) << 4;

    float c_r[4] = {0.f, 0.f, 0.f, 0.f};
    float* out_t = out;

    #define SB __builtin_amdgcn_sched_barrier(0);

    #define POLL(q)                                                              \
        { unsigned int fv;                                                       \
          for (;;) {                                                             \
            asm volatile("global_load_dword %0, %1, off sc0 sc1\n\t"             \
                         "s_waitcnt vmcnt(0)"                                    \
                         : "=v"(fv) : "v"(fp[q]) : "memory");                    \
            if (__all((int)(fv >= (unsigned int)t))) break;                      \
            __builtin_amdgcn_s_sleep(1);                                         \
          } }

    #define ISSUEA(buf, q)                                                       \
        _Pragma("unroll") for (int ki = 0; ki < 8; ++ki) {                       \
            const char* ap = aptr + ((q) * 8 + ki) * 64;                         \
            asm volatile("global_load_dwordx4 %0, %1, off sc0 sc1"               \
                         : "=v"(buf[ki]) : "v"(ap));                             \
        }

    #define QCOMP(areg, q)                                                       \
        _Pragma("unroll") for (int ki = 0; ki < 8; ++ki) {                       \
            const int ks = (q) * 8 + ki;                                         \
            const char* bc = bbase + ks * 4096;                                  \
            bf16x8 bw0 = *(const bf16x8*)(bc);                                   \
            bf16x8 bw1 = *(const bf16x8*)(bc + 1024);                            \
            bf16x8 bw2 = *(const bf16x8*)(bc + 2048);                            \
            bf16x8 bw3 = *(const bf16x8*)(bc + 3072);                            \
            acc[0] = __builtin_amdgcn_mfma_f32_16x16x32_bf16(areg[ki], bw0, acc[0], 0, 0, 0); \
            acc[1] = __builtin_amdgcn_mfma_f32_16x16x32_bf16(areg[ki], bw1, acc[1], 0, 0, 0); \
            acc[2] = __builtin_amdgcn_mfma_f32_16x16x32_bf16(areg[ki], bw2, acc[2], 0, 0, 0); \
            acc[3] = __builtin_amdgcn_mfma_f32_16x16x32_bf16(areg[ki], bw3, acc[3], 0, 0, 0); \
        }

    for (int t = 0; t < TT; ++t) {
        const char* aptr = (t & 1) ? aptr1 : aptr0;
        unsigned short* hout = (t & 1) ? hb0 : hb1;
        const int* xt = x + t * BB;

        f32x4 acc[4];
        #pragma unroll
        for (int nf = 0; nf < 4; ++nf) acc[nf] = (f32x4){0.f, 0.f, 0.f, 0.f};
        bf16x8 bufA[8], bufB[8];

        int4 xv;
        asm volatile("global_load_dwordx4 %0, %1, off sc0 sc1"
                     : "=v"(xv) : "v"(xt + b0));

        POLL(0)                     // vmcnt(0) inside: x resident after this
        ISSUEA(bufA, 0)
        POLL(1)                     // drains bufA
        ISSUEA(bufB, 1)
        SB QCOMP(bufA, 0) SB
        POLL(2)                     // drains bufB
        ISSUEA(bufA, 2)
        SB QCOMP(bufB, 1) SB
        POLL(3)                     // drains bufA(2)
        ISSUEA(bufB, 3)
        // gp gather (overlaps Q2; covered by the vmcnt(0) before Q3)
        float4 gpv[4];
        {
            const int vr[4] = {xv.x, xv.y, xv.z, xv.w};
            #pragma unroll
            for (int r = 0; r < 4; ++r) {
                const float* gpp = gp2 + ((size_t)vr[r] * LL + l) * 4;
                asm volatile("global_load_dwordx4 %0, %1, off"
                             : "=v"(gpv[r]) : "v"(gpp));
            }
        }
        SB QCOMP(bufA, 2) SB
        asm volatile("s_waitcnt vmcnt(0)" ::: "memory");
        SB
        QCOMP(bufB, 3)

        // ---- epilogue: c in regs; out plain stores; h write-through stores ----
        #pragma unroll
        for (int r = 0; r < 4; ++r) {
            const float gf = acc[0][r] + gpv[r].x;
            const float gi = acc[1][r] + gpv[r].y;
            const float go = acc[2][r] + gpv[r].z;
            const float gc = acc[3][r] + gpv[r].w;
            const float cn = sigmoidf_(gf) * c_r[r] + sigmoidf_(gi) * tanhf_(gc);
            const float hn = sigmoidf_(go) * tanhf_(cn);
            c_r[r] = cn;
            const size_t off = (size_t)(b0 + r) * LL + l;
            out_t[off] = hn;
            unsigned int hbits = f2bf(hn);
            const unsigned short* hp = hout + off;
            asm volatile("global_store_short %0, %1, off sc0 sc1"
                         :: "v"(hp), "v"(hbits) : "memory");
        }

        asm volatile("s_waitcnt vmcnt(0)" ::: "memory");
        __syncthreads();
        if (t < TT - 1 && tid == 0)
            atomicExch(&flags[myflag], (unsigned int)(t + 1));
        out_t += BB * LL;
    }

    #undef SB
    #undef POLL
    #undef ISSUEA
    #undef QCOMP
}

// ---------------- launch ----------------
extern "C" void kernel_launch(void* const* d_in, const int* in_sizes, int n_in,
                              void* d_out, int out_size, void* d_ws, size_t ws_size,
                              hipStream_t stream) {
    const int*   x      = (const int*)d_in[0];
    const float* h_init = (const float*)d_in[1];
    const float* emb    = (const float*)d_in[2];
    const float* Wf     = (const float*)d_in[3];
    const float* bfv    = (const float*)d_in[4];
    const float* Wi     = (const float*)d_in[5];
    const float* biv    = (const float*)d_in[6];
    const float* Wo     = (const float*)d_in[7];
    const float* bov    = (const float*)d_in[8];
    const float* Wc     = (const float*)d_in[9];
    const float* bcv    = (const float*)d_in[10];
    float* out = (float*)d_out;

    char* ws = (char*)d_ws;
    unsigned short* Wimg    = (unsigned short*)(ws);                 // 8 MB
    unsigned short* Wemb_hi = (unsigned short*)(ws + 8388608);       // 8 MB
    unsigned short* Wemb_lo = (unsigned short*)(ws + 16777216);      // 8 MB
    unsigned short* Eh      = (unsigned short*)(ws + 25165824);      // 192 KB
    unsigned short* El      = (unsigned short*)(ws + 25362432);      // 192 KB
    float*          gp2     = (float*)(ws + 25559040);               // 1.5 MB
    unsigned short* hb0     = (unsigned short*)(ws + 27131904);      // 512 KB
    unsigned short* hb1     = (unsigned short*)(ws + 27656192);      // 512 KB
    unsigned int*   flags   = (unsigned int*)(ws + 28180480);        // 16 KB

    prep_w_all<<<4096, 256, 0, stream>>>(Wf, Wi, Wo, Wc, Wimg, Wemb_hi, Wemb_lo);
    prep_emb_split<<<384, 256, 0, stream>>>(emb, Eh, El);
    gate_pre_mfma<<<64, 128, 0, stream>>>(Eh, El, Wemb_hi, Wemb_lo,
                                          bfv, biv, bov, bcv, gp2);
    init_state<<<1024, 256, 0, stream>>>(h_init, hb0, flags);

    void* kargs[] = {(void*)&Wimg, (void*)&gp2, (void*)&x,
                     (void*)&hb0, (void*)&hb1, (void*)&out, (void*)&flags};
    hipLaunchCooperativeKernel(reinterpret_cast<void*>(lstm_all),
                               dim3(256), dim3(256), kargs, 0, stream);
}

// Round 11
// 965.242 us; speedup vs baseline: 1.7582x; 1.0753x over previous
//
#include <hip/hip_runtime.h>
#include <stdint.h>

// ---------------- problem constants ----------------
constexpr int TT = 128;    // time steps
constexpr int BB = 256;    // batch
constexpr int LL = 1024;   // hidden dim
constexpr int NG = 4096;   // 4 gates * LL
constexpr int VV = 95;     // vocab

typedef short bf16x8 __attribute__((ext_vector_type(8)));
typedef float f32x4  __attribute__((ext_vector_type(4)));

typedef __attribute__((address_space(1))) const uint32_t gu32;
typedef __attribute__((address_space(3))) uint32_t lu32;

__device__ __forceinline__ unsigned short f2bf(float f) {
    unsigned int u = __builtin_bit_cast(unsigned int, f);
    unsigned int r = (u + 0x7FFFu + ((u >> 16) & 1u)) >> 16;
    return (unsigned short)r;
}
__device__ __forceinline__ float bf2f(unsigned short h) {
    unsigned int u = ((unsigned int)h) << 16;
    return __builtin_bit_cast(float, u);
}
__device__ __forceinline__ float sigmoidf_(float x) {
    return 1.0f / (1.0f + __expf(-x));
}
__device__ __forceinline__ float tanhf_(float x) {
    return 1.0f - 2.0f / (__expf(2.0f * x) + 1.0f);
}

// ---------------- prep: W split (R4 image layout + bank swizzle) ----------------
// Recurrent half -> Wimg, per-lt LDS image (131072 B):
//   nl = gate*16 + (l&15); kslot = (k>>3)&3 swizzled by row: kslot' = kslot ^ (nl&3)
//   byte = lt*131072 + (k>>5)*4096 + nl*64 + (kslot'<<4) + (k&7)*2
// Embedding half -> Wemb hi/lo, row-major [row][k], row = lt*64 + nl.
__global__ void prep_w_all(const float* __restrict__ Wf, const float* __restrict__ Wi,
                           const float* __restrict__ Wo, const float* __restrict__ Wc,
                           unsigned short* __restrict__ Wimg,
                           unsigned short* __restrict__ Wemb_hi,
                           unsigned short* __restrict__ Wemb_lo) {
    int idx = blockIdx.x * 256 + threadIdx.x;
    const int total = NG * 2048;  // 8M
    for (; idx < total; idx += gridDim.x * 256) {
        int row = idx >> 11;        // 0..4095
        int col = idx & 2047;       // 0..2047
        int lt   = row >> 6;
        int nl   = row & 63;
        int gate = nl >> 4;
        int l    = lt * 16 + (nl & 15);
        const float* W = (gate == 0) ? Wf : (gate == 1) ? Wi : (gate == 2) ? Wo : Wc;
        float w = W[l * 2048 + col];
        if (col >= 1024) {
            int k = col - 1024;
            int ksl = ((k >> 3) & 3) ^ (nl & 3);
            size_t byte = (size_t)lt * 131072 + (size_t)(k >> 5) * 4096 + nl * 64
                        + (ksl << 4) + (k & 7) * 2;
            *(unsigned short*)((char*)Wimg + byte) = f2bf(w);
        } else {
            unsigned short hi = f2bf(w);
            float lo = w - bf2f(hi);
            Wemb_hi[row * 1024 + col] = hi;
            Wemb_lo[row * 1024 + col] = f2bf(lo);
        }
    }
}

// ---------------- prep: emb hi/lo split, padded to 96 rows ----------------
__global__ void prep_emb_split(const float* __restrict__ emb,
                               unsigned short* __restrict__ Eh,
                               unsigned short* __restrict__ El) {
    int idx = blockIdx.x * 256 + threadIdx.x;   // 96*1024 threads
    int v = idx >> 10;
    float w = (v < VV) ? emb[idx] : 0.0f;
    unsigned short hi = f2bf(w);
    Eh[idx] = hi;
    El[idx] = f2bf(w - bf2f(hi));
}

// ---------------- prep: gate_pre2[v][l][gate] via hi/lo MFMA ----------------
__global__ __launch_bounds__(128)
void gate_pre_mfma(const unsigned short* __restrict__ Eh, const unsigned short* __restrict__ El,
                   const unsigned short* __restrict__ Wh, const unsigned short* __restrict__ Wl,
                   const float* __restrict__ bfv, const float* __restrict__ biv,
                   const float* __restrict__ bov, const float* __restrict__ bcv,
                   float* __restrict__ gp2) {
    const int lt   = blockIdx.x;
    const int tid  = threadIdx.x;
    const int lane = tid & 63;
    const int wm   = tid >> 6;
    const int l15  = lane & 15;
    const int kq   = lane >> 4;          // 0..3

    f32x4 acc[3][4];
    #pragma unroll
    for (int mf = 0; mf < 3; ++mf)
        #pragma unroll
        for (int nf = 0; nf < 4; ++nf) acc[mf][nf] = (f32x4){0.f, 0.f, 0.f, 0.f};

    #pragma unroll 2
    for (int ks = 0; ks < 32; ++ks) {
        const int k0 = ks * 32 + kq * 8;
        bf16x8 ah[3], al[3], bh[4], bl[4];
        #pragma unroll
        for (int mf = 0; mf < 3; ++mf) {
            const size_t ao = (size_t)(wm * 48 + mf * 16 + l15) * 1024 + k0;
            ah[mf] = *(const bf16x8*)(Eh + ao);
            al[mf] = *(const bf16x8*)(El + ao);
        }
        #pragma unroll
        for (int nf = 0; nf < 4; ++nf) {
            const size_t bo = (size_t)(lt * 64 + nf * 16 + l15) * 1024 + k0;
            bh[nf] = *(const bf16x8*)(Wh + bo);
            bl[nf] = *(const bf16x8*)(Wl + bo);
        }
        #pragma unroll
        for (int mf = 0; mf < 3; ++mf)
            #pragma unroll
            for (int nf = 0; nf < 4; ++nf) {
                acc[mf][nf] = __builtin_amdgcn_mfma_f32_16x16x32_bf16(ah[mf], bh[nf], acc[mf][nf], 0, 0, 0);
                acc[mf][nf] = __builtin_amdgcn_mfma_f32_16x16x32_bf16(ah[mf], bl[nf], acc[mf][nf], 0, 0, 0);
                acc[mf][nf] = __builtin_amdgcn_mfma_f32_16x16x32_bf16(al[mf], bh[nf], acc[mf][nf], 0, 0, 0);
            }
    }

    const int lgl = lt * 16 + l15;
    #pragma unroll
    for (int nf = 0; nf < 4; ++nf) {
        const float* bias = (nf == 0) ? bfv : (nf == 1) ? biv : (nf == 2) ? bov : bcv;
        const float bv = bias[lgl];
        #pragma unroll
        for (int mf = 0; mf < 3; ++mf)
            #pragma unroll
            for (int r = 0; r < 4; ++r) {
                const int v = wm * 48 + mf * 16 + kq * 4 + r;
                if (v < VV)
                    gp2[((size_t)v * LL + lgl) * 4 + nf] = acc[mf][nf][r] + bv;
            }
    }
}

// ---------------- prep: init h0 (bf16) and zero sync flags ----------------
__global__ void init_state(const float* __restrict__ h_init,
                           unsigned short* __restrict__ h0,
                           unsigned int* __restrict__ flags) {
    int idx = blockIdx.x * 256 + threadIdx.x;   // 1024*256 = BB*LL
    h0[idx] = f2bf(h_init[idx]);
    if (idx < 4096) flags[idx] = 0;             // 256 block-flags, 64B-strided
}

// ---------------- persistent LSTM, flag-synced, conflict-free, 1 poll/step ----
// grid 256 (bt=blk>>6, lt=blk&63) cooperative, 256 thr = 4 waves.
// W LDS-resident (swizzled) for all 128 steps; c in registers; barrier-free
// K-loop with counted vmcnt; single 64-flag poll per step.
// All inline-asm load dests are EARLY-CLOBBER ("=&v"): without it the allocator
// may alias the dest with the (long-lived) address pair -> garbage address on
// the next poll/step -> page fault (R10 crash).
__global__ __launch_bounds__(256, 1)
void lstm_all3(const unsigned short* __restrict__ Wimg,
               const float* __restrict__ gp2,
               const int* __restrict__ x,
               unsigned short* __restrict__ hb0,
               unsigned short* __restrict__ hb1,
               float* __restrict__ out,
               unsigned int* __restrict__ flags) {
    __shared__ unsigned short wlds_s[65536];   // 128 KiB
    char* wlds = (char*)wlds_s;

    const int tid  = threadIdx.x;
    const int lane = tid & 63;
    const int wv   = tid >> 6;
    const int bt   = blockIdx.x >> 6;
    const int lt   = blockIdx.x & 63;
    const int l15  = lane & 15;
    const int kq   = lane >> 4;

    const int l  = lt * 16 + l15;
    const int b0 = bt * 64 + wv * 16 + kq * 4;

    // ---- stage W into LDS once (linear copy; swizzle baked into image) ----
    {
        const char* wsrc = (const char*)Wimg + (size_t)lt * 131072 + tid * 16;
        #pragma unroll
        for (int j = 0; j < 32; ++j)
            __builtin_amdgcn_global_load_lds((gu32*)(wsrc + j * 4096),
                                             (lu32*)(wlds + j * 4096 + wv * 1024),
                                             16, 0, 0);
        asm volatile("s_waitcnt vmcnt(0)" ::: "memory");
        __syncthreads();
    }
    // swizzled B-frag base: row l15, k-slot kq^(l15&3)
    const char* bbase = wlds + l15 * 64 + ((kq ^ (l15 & 3)) << 4);

    // per-step-invariant addresses
    const size_t arow = (size_t)(bt * 64 + wv * 16 + l15) * 2048 + kq * 16;
    const char* aptr0 = (const char*)hb0 + arow;
    const char* aptr1 = (const char*)hb1 + arow;
    const unsigned int* fpoll = flags + (((bt << 6) + lane) << 4);  // lane -> producer lt
    const int myflag = ((bt << 6) + lt) << 4;

    float c_r[4] = {0.f, 0.f, 0.f, 0.f};
    float* out_t = out;

    #define SB __builtin_amdgcn_sched_barrier(0);

    #define POLLALL()                                                            \
        { unsigned int fv;                                                       \
          for (;;) {                                                             \
            asm volatile("global_load_dword %0, %1, off sc0 sc1\n\t"             \
                         "s_waitcnt vmcnt(0)"                                    \
                         : "=&v"(fv) : "v"(fpoll) : "memory");                   \
            if (__all((int)(fv >= (unsigned int)t))) break;                      \
            __builtin_amdgcn_s_sleep(1);                                         \
          } }

    #define ISSUEA(buf, q)                                                       \
        _Pragma("unroll") for (int ki = 0; ki < 8; ++ki) {                       \
            const char* ap = aptr + ((q) * 8 + ki) * 64;                         \
            asm volatile("global_load_dwordx4 %0, %1, off sc0 sc1"               \
                         : "=&v"(buf[ki]) : "v"(ap));                            \
        }

    #define QCOMP(areg, q)                                                       \
        _Pragma("unroll") for (int ki = 0; ki < 8; ++ki) {                       \
            const int ks = (q) * 8 + ki;                                         \
            const char* bc = bbase + ks * 4096;                                  \
            bf16x8 bw0 = *(const bf16x8*)(bc);                                   \
            bf16x8 bw1 = *(const bf16x8*)(bc + 1024);                            \
            bf16x8 bw2 = *(const bf16x8*)(bc + 2048);                            \
            bf16x8 bw3 = *(const bf16x8*)(bc + 3072);                            \
            acc[0] = __builtin_amdgcn_mfma_f32_16x16x32_bf16(areg[ki], bw0, acc[0], 0, 0, 0); \
            acc[1] = __builtin_amdgcn_mfma_f32_16x16x32_bf16(areg[ki], bw1, acc[1], 0, 0, 0); \
            acc[2] = __builtin_amdgcn_mfma_f32_16x16x32_bf16(areg[ki], bw2, acc[2], 0, 0, 0); \
            acc[3] = __builtin_amdgcn_mfma_f32_16x16x32_bf16(areg[ki], bw3, acc[3], 0, 0, 0); \
        }

    #define WAITV(N) asm volatile("s_waitcnt vmcnt(" #N ")" ::: "memory");

    for (int t = 0; t < TT; ++t) {
        const char* aptr = (t & 1) ? aptr1 : aptr0;
        unsigned short* hout = (t & 1) ? hb0 : hb1;
        const int* xt = x + t * BB;

        f32x4 acc[4];
        #pragma unroll
        for (int nf = 0; nf < 4; ++nf) acc[nf] = (f32x4){0.f, 0.f, 0.f, 0.f};
        bf16x8 bufA[8], bufB[8];

        POLLALL()                              // vm queue empty after this
        SB

        int4 xv;
        {
            const int* xp = xt + b0;
            asm volatile("global_load_dwordx4 %0, %1, off"
                         : "=&v"(xv) : "v"(xp));       // x: read-only, L2 ok
        }
        ISSUEA(bufA, 0)
        ISSUEA(bufB, 1)
        SB
        WAITV(8)                               // x + A0 resident; A1 in flight
        SB
        // gp gather (x now in regs); overlaps Q0..Q2
        float4 gpv[4];
        {
            const int vr[4] = {xv.x, xv.y, xv.z, xv.w};
            #pragma unroll
            for (int r = 0; r < 4; ++r) {
                const float* gpp = gp2 + ((size_t)vr[r] * LL + l) * 4;
                asm volatile("global_load_dwordx4 %0, %1, off"
                             : "=&v"(gpv[r]) : "v"(gpp));
            }
        }
        SB
        QCOMP(bufA, 0) SB
        ISSUEA(bufA, 2) SB
        WAITV(12)                              // A1 done; gp(4)+A2(8) in flight
        SB
        QCOMP(bufB, 1) SB
        ISSUEA(bufB, 3) SB
        WAITV(8)                               // gp+A2 done; A3 in flight
        SB
        QCOMP(bufA, 2) SB
        WAITV(0)                               // A3 done
        SB
        QCOMP(bufB, 3)

        // ---- epilogue: c in regs; h write-through first, out rides the queue ----
        float hnew[4];
        #pragma unroll
        for (int r = 0; r < 4; ++r) {
            const float gf = acc[0][r] + gpv[r].x;
            const float gi = acc[1][r] + gpv[r].y;
            const float go = acc[2][r] + gpv[r].z;
            const float gc = acc[3][r] + gpv[r].w;
            const float cn = sigmoidf_(gf) * c_r[r] + sigmoidf_(gi) * tanhf_(gc);
            hnew[r] = sigmoidf_(go) * tanhf_(cn);
            c_r[r] = cn;
        }
        #pragma unroll
        for (int r = 0; r < 4; ++r) {
            const size_t off = (size_t)(b0 + r) * LL + l;
            unsigned int hbits = f2bf(hnew[r]);
            const unsigned short* hp = hout + off;
            asm volatile("global_store_short %0, %1, off sc0 sc1"
                         :: "v"(hp), "v"(hbits) : "memory");
        }
        #pragma unroll
        for (int r = 0; r < 4; ++r)
            out_t[(size_t)(b0 + r) * LL + l] = hnew[r];

        WAITV(4)                               // h stores done; out still in flight
        __syncthreads();
        if (t < TT - 1 && tid == 0)
            atomicExch(&flags[myflag], (unsigned int)(t + 1));
        out_t += BB * LL;
    }

    #undef SB
    #undef POLLALL
    #undef ISSUEA
    #undef QCOMP
    #undef WAITV
}

// ---------------- launch ----------------
extern "C" void kernel_launch(void* const* d_in, const int* in_sizes, int n_in,
                              void* d_out, int out_size, void* d_ws, size_t ws_size,
                              hipStream_t stream) {
    const int*   x      = (const int*)d_in[0];
    const float* h_init = (const float*)d_in[1];
    const float* emb    = (const float*)d_in[2];
    const float* Wf     = (const float*)d_in[3];
    const float* bfv    = (const float*)d_in[4];
    const float* Wi     = (const float*)d_in[5];
    const float* biv    = (const float*)d_in[6];
    const float* Wo     = (const float*)d_in[7];
    const float* bov    = (const float*)d_in[8];
    const float* Wc     = (const float*)d_in[9];
    const float* bcv    = (const float*)d_in[10];
    float* out = (float*)d_out;

    char* ws = (char*)d_ws;
    unsigned short* Wimg    = (unsigned short*)(ws);                 // 8 MB
    unsigned short* Wemb_hi = (unsigned short*)(ws + 8388608);       // 8 MB
    unsigned short* Wemb_lo = (unsigned short*)(ws + 16777216);      // 8 MB
    unsigned short* Eh      = (unsigned short*)(ws + 25165824);      // 192 KB
    unsigned short* El      = (unsigned short*)(ws + 25362432);      // 192 KB
    float*          gp2     = (float*)(ws + 25559040);               // 1.5 MB
    unsigned short* hb0     = (unsigned short*)(ws + 27131904);      // 512 KB
    unsigned short* hb1     = (unsigned short*)(ws + 27656192);      // 512 KB
    unsigned int*   flags   = (unsigned int*)(ws + 28180480);        // 16 KB

    prep_w_all<<<4096, 256, 0, stream>>>(Wf, Wi, Wo, Wc, Wimg, Wemb_hi, Wemb_lo);
    prep_emb_split<<<384, 256, 0, stream>>>(emb, Eh, El);
    gate_pre_mfma<<<64, 128, 0, stream>>>(Eh, El, Wemb_hi, Wemb_lo,
                                          bfv, biv, bov, bcv, gp2);
    init_state<<<1024, 256, 0, stream>>>(h_init, hb0, flags);

    void* kargs[] = {(void*)&Wimg, (void*)&gp2, (void*)&x,
                     (void*)&hb0, (void*)&hb1, (void*)&out, (void*)&flags};
    hipLaunchCooperativeKernel(reinterpret_cast<void*>(lstm_all3),
                               dim3(256), dim3(256), kargs, 0, stream);
}